// Round 1
// baseline (27389.413 us; speedup 1.0000x reference)
//
#include <hip/hip_runtime.h>
#include <math.h>

// Problem: B=1024, T=512, I=2, H=256, G=4H=1024
// LSTM recurrence (batch-parallel) + 3-layer MLP head.

// ---------------- transpose: out[c][r] = in[r][c] ----------------
__global__ void transpose_kernel(const float* __restrict__ in,
                                 float* __restrict__ out,
                                 int rows, int cols)
{
    __shared__ float tile[32][33];
    const int c0 = blockIdx.x * 32;
    const int r0 = blockIdx.y * 32;
    const int tx = threadIdx.x;   // 0..31
    const int ty = threadIdx.y;   // 0..7
#pragma unroll
    for (int i = 0; i < 4; ++i) {
        tile[ty + i * 8][tx] = in[(r0 + ty + i * 8) * cols + (c0 + tx)];
    }
    __syncthreads();
#pragma unroll
    for (int i = 0; i < 4; ++i) {
        out[(c0 + ty + i * 8) * rows + (r0 + tx)] = tile[tx][ty + i * 8];
    }
}

// ---------------- LSTM kernel ----------------
// 128 blocks x 1024 threads. Block owns 8 batch rows.
// Phase A: thread (gq,kq) accumulates gates[r][g0..g0+3] over k in [64*kq, 64*kq+64)
//          for all 8 rows; partials combined via LDS atomic adds.
// Phase B: thread owns 2 (row, hidden-j) pairs: gate nonlinearities, c in regs,
//          h written to LDS for next step.
#define FMA_STEP(W, HC) \
    acc[r][0] = fmaf(W.x, HC, acc[r][0]); \
    acc[r][1] = fmaf(W.y, HC, acc[r][1]); \
    acc[r][2] = fmaf(W.z, HC, acc[r][2]); \
    acc[r][3] = fmaf(W.w, HC, acc[r][3]);

__global__ __launch_bounds__(1024, 4)
void lstm_kernel(const float* __restrict__ x,     // [B][T][2]
                 const float* __restrict__ WT,    // [256][1024]  WT[k][g] = W_hh[g][k]
                 const float* __restrict__ W_ih,  // [1024][2]
                 const float* __restrict__ b_ih,  // [1024]
                 const float* __restrict__ b_hh,  // [1024]
                 float* __restrict__ hT)          // [B][256] final hidden
{
    __shared__ float gates_lds[8 * 1024];
    __shared__ float h_lds[8 * 256];
    __shared__ float xs[16];

    const int tid = threadIdx.x;
    const int br  = blockIdx.x * 8;

    // phase-A mapping
    const int gq = tid & 255;  const int g0 = gq * 4;
    const int kq = tid >> 8;   const int k0 = kq * 64;

    // phase-B mapping: pairs (rb, j0), (rb, j0+1)
    const int rb = tid >> 7;            // 0..7
    const int j0 = (tid & 127) * 2;     // even 0..254

    // per-thread constants for phase B (gate order i,f,g,o packed along 4H)
    float bias[8], wx0[8], wx1[8];
#pragma unroll
    for (int jj = 0; jj < 2; ++jj)
#pragma unroll
        for (int gt = 0; gt < 4; ++gt) {
            const int g   = gt * 256 + j0 + jj;
            const int idx = jj * 4 + gt;
            bias[idx] = b_ih[g] + b_hh[g];
            wx0[idx]  = W_ih[2 * g + 0];
            wx1[idx]  = W_ih[2 * g + 1];
        }

    for (int i = tid; i < 8 * 256;  i += 1024) h_lds[i]     = 0.f;
    for (int i = tid; i < 8 * 1024; i += 1024) gates_lds[i] = 0.f;
    float cv0 = 0.f, cv1 = 0.f;
    __syncthreads();

    const float* wtp = WT + (size_t)k0 * 1024 + g0;

    for (int t = 0; t < 512; ++t) {
        // stage x[br..br+7][t][0..1]
        if (tid < 16) {
            xs[tid] = x[(size_t)(br + (tid >> 1)) * 1024 + t * 2 + (tid & 1)];
        }

        // ---- phase A: recurrent gate partials ----
        float acc[8][4];
#pragma unroll
        for (int r = 0; r < 8; ++r) {
            acc[r][0] = 0.f; acc[r][1] = 0.f; acc[r][2] = 0.f; acc[r][3] = 0.f;
        }

#pragma unroll 2
        for (int kk = 0; kk < 64; kk += 4) {
            const float4 w0 = *(const float4*)(wtp + (size_t)(kk + 0) * 1024);
            const float4 w1 = *(const float4*)(wtp + (size_t)(kk + 1) * 1024);
            const float4 w2 = *(const float4*)(wtp + (size_t)(kk + 2) * 1024);
            const float4 w3 = *(const float4*)(wtp + (size_t)(kk + 3) * 1024);
#pragma unroll
            for (int r = 0; r < 8; ++r) {
                const float4 hv = *(const float4*)&h_lds[r * 256 + k0 + kk];
                FMA_STEP(w0, hv.x)
                FMA_STEP(w1, hv.y)
                FMA_STEP(w2, hv.z)
                FMA_STEP(w3, hv.w)
            }
        }

#pragma unroll
        for (int r = 0; r < 8; ++r) {
#pragma unroll
            for (int j = 0; j < 4; ++j) {
                unsafeAtomicAdd(&gates_lds[r * 1024 + g0 + j], acc[r][j]);
            }
        }
        __syncthreads();

        // ---- phase B: nonlinearity + state update ----
        const float xv0 = xs[rb * 2 + 0];
        const float xv1 = xs[rb * 2 + 1];

        float hw0, hw1;
        {
            // jj = 0
            float s[4];
#pragma unroll
            for (int gt = 0; gt < 4; ++gt) {
                const int g   = gt * 256 + j0;
                const int idx = gt;
                s[gt] = bias[idx] + gates_lds[rb * 1024 + g]
                      + xv0 * wx0[idx] + xv1 * wx1[idx];
                gates_lds[rb * 1024 + g] = 0.f;  // re-zero for next step
            }
            const float gi = 1.f / (1.f + expf(-s[0]));
            const float gf = 1.f / (1.f + expf(-s[1]));
            const float gg = tanhf(s[2]);
            const float go = 1.f / (1.f + expf(-s[3]));
            cv0 = gf * cv0 + gi * gg;
            hw0 = go * tanhf(cv0);
            h_lds[rb * 256 + j0] = hw0;
        }
        {
            // jj = 1
            float s[4];
#pragma unroll
            for (int gt = 0; gt < 4; ++gt) {
                const int g   = gt * 256 + j0 + 1;
                const int idx = 4 + gt;
                s[gt] = bias[idx] + gates_lds[rb * 1024 + g]
                      + xv0 * wx0[idx] + xv1 * wx1[idx];
                gates_lds[rb * 1024 + g] = 0.f;
            }
            const float gi = 1.f / (1.f + expf(-s[0]));
            const float gf = 1.f / (1.f + expf(-s[1]));
            const float gg = tanhf(s[2]);
            const float go = 1.f / (1.f + expf(-s[3]));
            cv1 = gf * cv1 + gi * gg;
            hw1 = go * tanhf(cv1);
            h_lds[rb * 256 + j0 + 1] = hw1;
        }

        if (t == 511) {
            hT[(size_t)(br + rb) * 256 + j0 + 0] = hw0;
            hT[(size_t)(br + rb) * 256 + j0 + 1] = hw1;
        }
        __syncthreads();
    }
}

// ---------------- MLP head ----------------
// 128 blocks x 256 threads, 8 rows per block.
__global__ void mlp_kernel(const float* __restrict__ hT,   // [B][256]
                           const float* __restrict__ W1T,  // [256][256] W1T[k][j]=W1[j][k]
                           const float* __restrict__ b1,
                           const float* __restrict__ W2T,  // [256][256]
                           const float* __restrict__ b2,
                           const float* __restrict__ W3,   // [256]
                           const float* __restrict__ b3,   // [1]
                           float* __restrict__ out)        // [B]
{
    __shared__ float hs[8][256];
    __shared__ float a1[8][256];
    __shared__ float a2[8][256];
    __shared__ float p3[8][257];

    const int tid = threadIdx.x;
    const int br  = blockIdx.x * 8;

#pragma unroll
    for (int r = 0; r < 8; ++r) hs[r][tid] = hT[(size_t)(br + r) * 256 + tid];
    __syncthreads();

    // layer 1
    {
        float acc[8];
#pragma unroll
        for (int r = 0; r < 8; ++r) acc[r] = b1[tid];
        for (int k = 0; k < 256; k += 4) {
            const float w0 = W1T[(k + 0) * 256 + tid];
            const float w1 = W1T[(k + 1) * 256 + tid];
            const float w2 = W1T[(k + 2) * 256 + tid];
            const float w3 = W1T[(k + 3) * 256 + tid];
#pragma unroll
            for (int r = 0; r < 8; ++r) {
                const float4 hv = *(const float4*)&hs[r][k];
                acc[r] = fmaf(w0, hv.x, acc[r]);
                acc[r] = fmaf(w1, hv.y, acc[r]);
                acc[r] = fmaf(w2, hv.z, acc[r]);
                acc[r] = fmaf(w3, hv.w, acc[r]);
            }
        }
#pragma unroll
        for (int r = 0; r < 8; ++r) a1[r][tid] = fmaxf(acc[r], 0.f);
    }
    __syncthreads();

    // layer 2
    {
        float acc[8];
#pragma unroll
        for (int r = 0; r < 8; ++r) acc[r] = b2[tid];
        for (int k = 0; k < 256; k += 4) {
            const float w0 = W2T[(k + 0) * 256 + tid];
            const float w1 = W2T[(k + 1) * 256 + tid];
            const float w2 = W2T[(k + 2) * 256 + tid];
            const float w3 = W2T[(k + 3) * 256 + tid];
#pragma unroll
            for (int r = 0; r < 8; ++r) {
                const float4 hv = *(const float4*)&a1[r][k];
                acc[r] = fmaf(w0, hv.x, acc[r]);
                acc[r] = fmaf(w1, hv.y, acc[r]);
                acc[r] = fmaf(w2, hv.z, acc[r]);
                acc[r] = fmaf(w3, hv.w, acc[r]);
            }
        }
#pragma unroll
        for (int r = 0; r < 8; ++r) a2[r][tid] = fmaxf(acc[r], 0.f);
    }
    __syncthreads();

    // layer 3 partials
    {
        const float w = W3[tid];
#pragma unroll
        for (int r = 0; r < 8; ++r) p3[r][tid] = w * a2[r][tid];
    }
    __syncthreads();
    if (tid < 8) {
        float s = 0.f;
        for (int k = 0; k < 256; ++k) s += p3[tid][k];
        out[br + tid] = s + b3[0];
    }
}

// ---------------- launcher ----------------
extern "C" void kernel_launch(void* const* d_in, const int* in_sizes, int n_in,
                              void* d_out, int out_size, void* d_ws, size_t ws_size,
                              hipStream_t stream)
{
    const float* x    = (const float*)d_in[0];
    const float* W_ih = (const float*)d_in[1];
    const float* W_hh = (const float*)d_in[2];
    const float* b_ih = (const float*)d_in[3];
    const float* b_hh = (const float*)d_in[4];
    const float* W1   = (const float*)d_in[5];
    const float* b1   = (const float*)d_in[6];
    const float* W2   = (const float*)d_in[7];
    const float* b2   = (const float*)d_in[8];
    const float* W3   = (const float*)d_in[9];
    const float* b3   = (const float*)d_in[10];

    // workspace layout (fp32): WT 1MB | hT 1MB | W1T 256KB | W2T 256KB
    float* WT  = (float*)d_ws;             // 256*1024
    float* hT  = WT  + 256 * 1024;         // 1024*256
    float* W1T = hT  + 1024 * 256;         // 256*256
    float* W2T = W1T + 256 * 256;          // 256*256

    transpose_kernel<<<dim3(8, 32), dim3(32, 8), 0, stream>>>(W_hh, WT, 1024, 256);
    transpose_kernel<<<dim3(8, 8),  dim3(32, 8), 0, stream>>>(W1, W1T, 256, 256);
    transpose_kernel<<<dim3(8, 8),  dim3(32, 8), 0, stream>>>(W2, W2T, 256, 256);

    lstm_kernel<<<128, 1024, 0, stream>>>(x, WT, W_ih, b_ih, b_hh, hT);
    mlp_kernel<<<128, 256, 0, stream>>>(hT, W1T, b1, W2T, b2, W3, b3, (float*)d_out);
}

// Round 3
// 3828.128 us; speedup vs baseline: 7.1548x; 7.1548x over previous
//
#include <hip/hip_runtime.h>
#include <math.h>

// B=1024, T=512, I=2, H=256, G=4H=1024
// LSTM: 64 blocks x 1024 threads (16 waves), 16 batch rows per block.
// W_hh bf16, pre-packed fragment-major; kt 0-1 cached in LDS (128 KB), kt 2-7
// streamed from L2 each step. h kept as bf16 hi+lo in swizzled LDS (2 MFMA
// products per W frag => full fp32-ish accuracy on the recurrent path).
// Wave wv owns units [16wv,16wv+16) x all 4 gate types, so each lane's MFMA
// D-fragment holds gate preacts i,f,g,o for its (row,unit) cells ->
// nonlinearity entirely in registers, no gates LDS buffer.

typedef __attribute__((ext_vector_type(8))) short bf16x8;
typedef __attribute__((ext_vector_type(4))) float f32x4;

#define MFMA16(a, b, c) __builtin_amdgcn_mfma_f32_16x16x32_bf16((a), (b), (c), 0, 0, 0)

__device__ __forceinline__ ushort f2bf(float f) {
    union { float f; unsigned u; } v; v.f = f;
    unsigned r = v.u + 0x7fffu + ((v.u >> 16) & 1u);
    return (ushort)(r >> 16);
}
__device__ __forceinline__ float bf2f(ushort b) {
    union { unsigned u; float f; } v; v.u = ((unsigned)b) << 16; return v.f;
}
__device__ __forceinline__ float fsig(float x)  { return 1.f / (1.f + __expf(-x)); }
__device__ __forceinline__ float ftanh_(float x){ return 2.f / (1.f + __expf(-2.f * x)) - 1.f; }

// ---------------- W_hh fragment packing ----------------
// wfrag element index = f*512 + lane*8, f = (wv*8 + kt)*4 + gt
// value[i] = bf16( W_hh[ gt*256 + wv*16 + (lane&15) ][ kt*32 + (lane>>4)*8 + i ] )
__global__ void pack_whh(const float* __restrict__ W, ushort* __restrict__ wf)
{
    const int idx  = blockIdx.x * 256 + threadIdx.x;   // 0..32767
    const int lane = idx & 63;
    const int f    = idx >> 6;                          // 0..511
    const int gt   = f & 3;
    const int kt   = (f >> 2) & 7;
    const int wv   = f >> 5;
    const int g    = gt * 256 + wv * 16 + (lane & 15);
    const int k0   = kt * 32 + (lane >> 4) * 8;
    const float* src = W + (size_t)g * 256 + k0;
    bf16x8 v;
#pragma unroll
    for (int i = 0; i < 8; ++i) v[i] = (short)f2bf(src[i]);
    *(bf16x8*)(wf + (size_t)idx * 8) = v;
}

// ---------------- transpose: out[c][r] = in[r][c] ----------------
__global__ void transpose_kernel(const float* __restrict__ in,
                                 float* __restrict__ out,
                                 int rows, int cols)
{
    __shared__ float tile[32][33];
    const int c0 = blockIdx.x * 32;
    const int r0 = blockIdx.y * 32;
    const int tx = threadIdx.x;
    const int ty = threadIdx.y;
#pragma unroll
    for (int i = 0; i < 4; ++i)
        tile[ty + i * 8][tx] = in[(r0 + ty + i * 8) * cols + (c0 + tx)];
    __syncthreads();
#pragma unroll
    for (int i = 0; i < 4; ++i)
        out[(c0 + ty + i * 8) * rows + (r0 + tx)] = tile[tx][ty + i * 8];
}

// ---------------- LSTM kernel ----------------
__global__ __launch_bounds__(1024)
void lstm_kernel(const float* __restrict__ x,      // [B][T][2]
                 const ushort* __restrict__ wfrag, // packed bf16 W_hh frags
                 const float* __restrict__ W_ih,   // [1024][2]
                 const float* __restrict__ b_ih,   // [1024]
                 const float* __restrict__ b_hh,   // [1024]
                 float* __restrict__ hT)           // [B][256]
{
    __shared__ ushort wcache[16 * 8 * 512];        // 128 KB: wave-local frags, kt 0..1
    __shared__ __align__(16) ushort hbuf[2 * 16 * 256]; // 16 KB: [hi|lo][row][unit]

    const int tid  = threadIdx.x;
    const int lane = tid & 63;
    const int wv   = tid >> 6;        // wave 0..15
    const int fm   = lane & 15;
    const int fc   = lane >> 4;
    const int br   = blockIdx.x * 16; // batch row base
    const int u    = wv * 16 + fm;    // unit this lane owns in phase B

    // per-lane gate constants (gate order i,f,g,o along 4H)
    float bias[4], wi0[4], wi1[4];
#pragma unroll
    for (int gt = 0; gt < 4; ++gt) {
        const int g = gt * 256 + u;
        bias[gt] = b_ih[g] + b_hh[g];
        wi0[gt]  = W_ih[2 * g + 0];
        wi1[gt]  = W_ih[2 * g + 1];
    }

    for (int i = tid; i < 2 * 16 * 256; i += 1024) hbuf[i] = 0;

    // fill this wave's wcache slice (kt = 0,1)
    const ushort* wf_wave = wfrag + (size_t)wv * 16384 + lane * 8;
    ushort* wcw = &wcache[(size_t)(wv * 8) * 512 + lane * 8];
#pragma unroll
    for (int q = 0; q < 8; ++q) {     // q = kt*4+gt for kt<2
        const bf16x8 v = *(const bf16x8*)(wf_wave + q * 512);
        *(bf16x8*)(wcw + q * 512) = v;
    }

    // A-read swizzled byte offsets (hi; lo = +8192)
    int aoff[8];
#pragma unroll
    for (int kt = 0; kt < 8; ++kt)
        aoff[kt] = (fm * 512 + kt * 64 + fc * 16) ^ ((fm & 7) << 4);
    // h-write byte offsets (hi; lo = +8192)
    int hoff[4];
#pragma unroll
    for (int r = 0; r < 4; ++r) {
        const int row = fc * 4 + r;
        hoff[r] = (row * 512 + u * 2) ^ ((row & 7) << 4);
    }

    const char* hbase = (const char*)hbuf;
    const float* xrow = x + (size_t)br * 1024;

    float c[4] = {0.f, 0.f, 0.f, 0.f};
    __syncthreads();

    for (int t = 0; t < 512; ++t) {
        f32x4 acc[4];
#pragma unroll
        for (int gt = 0; gt < 4; ++gt) acc[gt] = (f32x4){0.f, 0.f, 0.f, 0.f};

        // x for this step (consumed in phase B; latency hidden by MFMA phase)
        float xr0[4], xr1[4];
#pragma unroll
        for (int r = 0; r < 4; ++r) {
            const float2 xv = *(const float2*)(xrow + (size_t)(fc * 4 + r) * 1024 + 2 * t);
            xr0[r] = xv.x; xr1[r] = xv.y;
        }

        // preload streamed W for kt=2,3
        bf16x8 wb0[4], wb1[4];
#pragma unroll
        for (int gt = 0; gt < 4; ++gt) wb0[gt] = *(const bf16x8*)(wf_wave + (8  + gt) * 512);
#pragma unroll
        for (int gt = 0; gt < 4; ++gt) wb1[gt] = *(const bf16x8*)(wf_wave + (12 + gt) * 512);

        // kt 0,1 from LDS wcache (overlaps global-load latency)
#pragma unroll
        for (int kt = 0; kt < 2; ++kt) {
            const bf16x8 ah = *(const bf16x8*)(hbase + aoff[kt]);
            const bf16x8 al = *(const bf16x8*)(hbase + aoff[kt] + 8192);
#pragma unroll
            for (int gt = 0; gt < 4; ++gt) {
                const bf16x8 w = *(const bf16x8*)(wcw + (kt * 4 + gt) * 512);
                acc[gt] = MFMA16(ah, w, acc[gt]);
                acc[gt] = MFMA16(al, w, acc[gt]);
            }
        }

        // kt 2..7 streamed, 2-deep rolling buffer
#pragma unroll
        for (int kt = 2; kt < 8; ++kt) {
            const bf16x8 ah = *(const bf16x8*)(hbase + aoff[kt]);
            const bf16x8 al = *(const bf16x8*)(hbase + aoff[kt] + 8192);
            if ((kt & 1) == 0) {
#pragma unroll
                for (int gt = 0; gt < 4; ++gt) {
                    acc[gt] = MFMA16(ah, wb0[gt], acc[gt]);
                    acc[gt] = MFMA16(al, wb0[gt], acc[gt]);
                }
                if (kt + 2 < 8) {
#pragma unroll
                    for (int gt = 0; gt < 4; ++gt)
                        wb0[gt] = *(const bf16x8*)(wf_wave + ((kt + 2) * 4 + gt) * 512);
                }
            } else {
#pragma unroll
                for (int gt = 0; gt < 4; ++gt) {
                    acc[gt] = MFMA16(ah, wb1[gt], acc[gt]);
                    acc[gt] = MFMA16(al, wb1[gt], acc[gt]);
                }
                if (kt + 2 < 8) {
#pragma unroll
                    for (int gt = 0; gt < 4; ++gt)
                        wb1[gt] = *(const bf16x8*)(wf_wave + ((kt + 2) * 4 + gt) * 512);
                }
            }
        }
        __syncthreads();   // all waves done reading hbuf

        // ---- phase B: in-register nonlinearity; D row = fc*4 + reg, unit u ----
#pragma unroll
        for (int r = 0; r < 4; ++r) {
            const float si = acc[0][r] + fmaf(xr1[r], wi1[0], fmaf(xr0[r], wi0[0], bias[0]));
            const float sf = acc[1][r] + fmaf(xr1[r], wi1[1], fmaf(xr0[r], wi0[1], bias[1]));
            const float sg = acc[2][r] + fmaf(xr1[r], wi1[2], fmaf(xr0[r], wi0[2], bias[2]));
            const float so = acc[3][r] + fmaf(xr1[r], wi1[3], fmaf(xr0[r], wi0[3], bias[3]));
            const float gi = fsig(si);
            const float gf = fsig(sf);
            const float gg = ftanh_(sg);
            const float go = fsig(so);
            c[r] = gf * c[r] + gi * gg;
            const float h = go * ftanh_(c[r]);
            const ushort hh = f2bf(h);
            const ushort hl = f2bf(h - bf2f(hh));
            *(ushort*)((char*)hbuf + hoff[r])        = hh;
            *(ushort*)((char*)hbuf + hoff[r] + 8192) = hl;
            if (t == 511) hT[(size_t)(br + fc * 4 + r) * 256 + u] = h;
        }
        __syncthreads();
    }
}

// ---------------- MLP head ----------------
__global__ void mlp_kernel(const float* __restrict__ hT,
                           const float* __restrict__ W1T,  // [256][256] W1T[k][j]
                           const float* __restrict__ b1,
                           const float* __restrict__ W2T,
                           const float* __restrict__ b2,
                           const float* __restrict__ W3,   // [256]
                           const float* __restrict__ b3,
                           float* __restrict__ out)        // [B]
{
    __shared__ float hs[8][256];
    __shared__ float a1[8][256];
    __shared__ float a2[8][256];
    __shared__ float p3[8][257];

    const int tid = threadIdx.x;
    const int br  = blockIdx.x * 8;

#pragma unroll
    for (int r = 0; r < 8; ++r) hs[r][tid] = hT[(size_t)(br + r) * 256 + tid];
    __syncthreads();

    {
        float acc[8];
#pragma unroll
        for (int r = 0; r < 8; ++r) acc[r] = b1[tid];
        for (int k = 0; k < 256; k += 4) {
            const float w0 = W1T[(k + 0) * 256 + tid];
            const float w1 = W1T[(k + 1) * 256 + tid];
            const float w2 = W1T[(k + 2) * 256 + tid];
            const float w3 = W1T[(k + 3) * 256 + tid];
#pragma unroll
            for (int r = 0; r < 8; ++r) {
                const float4 hv = *(const float4*)&hs[r][k];
                acc[r] = fmaf(w0, hv.x, acc[r]);
                acc[r] = fmaf(w1, hv.y, acc[r]);
                acc[r] = fmaf(w2, hv.z, acc[r]);
                acc[r] = fmaf(w3, hv.w, acc[r]);
            }
        }
#pragma unroll
        for (int r = 0; r < 8; ++r) a1[r][tid] = fmaxf(acc[r], 0.f);
    }
    __syncthreads();

    {
        float acc[8];
#pragma unroll
        for (int r = 0; r < 8; ++r) acc[r] = b2[tid];
        for (int k = 0; k < 256; k += 4) {
            const float w0 = W2T[(k + 0) * 256 + tid];
            const float w1 = W2T[(k + 1) * 256 + tid];
            const float w2 = W2T[(k + 2) * 256 + tid];
            const float w3 = W2T[(k + 3) * 256 + tid];
#pragma unroll
            for (int r = 0; r < 8; ++r) {
                const float4 hv = *(const float4*)&a1[r][k];
                acc[r] = fmaf(w0, hv.x, acc[r]);
                acc[r] = fmaf(w1, hv.y, acc[r]);
                acc[r] = fmaf(w2, hv.z, acc[r]);
                acc[r] = fmaf(w3, hv.w, acc[r]);
            }
        }
#pragma unroll
        for (int r = 0; r < 8; ++r) a2[r][tid] = fmaxf(acc[r], 0.f);
    }
    __syncthreads();

    {
        const float w = W3[tid];
#pragma unroll
        for (int r = 0; r < 8; ++r) p3[r][tid] = w * a2[r][tid];
    }
    __syncthreads();
    if (tid < 8) {
        float s = 0.f;
        for (int k = 0; k < 256; ++k) s += p3[tid][k];
        out[br + tid] = s + b3[0];
    }
}

// ---------------- launcher ----------------
extern "C" void kernel_launch(void* const* d_in, const int* in_sizes, int n_in,
                              void* d_out, int out_size, void* d_ws, size_t ws_size,
                              hipStream_t stream)
{
    const float* x    = (const float*)d_in[0];
    const float* W_ih = (const float*)d_in[1];
    const float* W_hh = (const float*)d_in[2];
    const float* b_ih = (const float*)d_in[3];
    const float* b_hh = (const float*)d_in[4];
    const float* W1   = (const float*)d_in[5];
    const float* b1   = (const float*)d_in[6];
    const float* W2   = (const float*)d_in[7];
    const float* b2   = (const float*)d_in[8];
    const float* W3   = (const float*)d_in[9];
    const float* b3   = (const float*)d_in[10];

    // workspace: hT 1MB | W1T 256KB | W2T 256KB | wfrag 512KB  (total 2 MB)
    float*  hT    = (float*)d_ws;            // 1024*256
    float*  W1T   = hT + 1024 * 256;         // 256*256
    float*  W2T   = W1T + 256 * 256;         // 256*256
    ushort* wfrag = (ushort*)(W2T + 256 * 256);  // 512*512 bf16

    pack_whh<<<128, 256, 0, stream>>>(W_hh, wfrag);
    transpose_kernel<<<dim3(8, 8), dim3(32, 8), 0, stream>>>(W1, W1T, 256, 256);
    transpose_kernel<<<dim3(8, 8), dim3(32, 8), 0, stream>>>(W2, W2T, 256, 256);

    lstm_kernel<<<64, 1024, 0, stream>>>(x, wfrag, W_ih, b_ih, b_hh, hT);
    mlp_kernel<<<128, 256, 0, stream>>>(hT, W1T, b1, W2T, b2, W3, b3, (float*)d_out);
}